// Round 1
// baseline (12608.514 us; speedup 1.0000x reference)
//
#include <hip/hip_runtime.h>

// LeNet C3 connectivity: for each input channel, the 10 output channels it feeds.
constexpr int CL[6][10] = {
    {0, 4, 5, 6, 9, 10, 11, 12, 14, 15},   // cin 0
    {0, 1, 5, 6, 7, 10, 11, 12, 13, 15},   // cin 1
    {0, 1, 2, 6, 7, 8, 11, 13, 14, 15},    // cin 2
    {1, 2, 3, 6, 7, 8, 9, 12, 14, 15},     // cin 3
    {2, 3, 4, 7, 8, 9, 10, 12, 13, 15},    // cin 4
    {3, 4, 5, 8, 9, 10, 11, 13, 14, 15},   // cin 5
};

#define CIN   6
#define COUT  16
#define HW    512
#define TILE_W 64
#define TILE_H 16
#define IN_W  68   // TILE_W + 4 halo
#define IN_H  20   // TILE_H + 4 halo
#define BIAS_OFF 1536  // float offset of bias within d_ws

// Pack masked weights into ws as wpk[cin][dx][dy][j(0..9)] (1500 floats),
// bias at float offset 1536 (16 floats). All-uniform layout so the main
// kernel's weight reads are scalar (SGPR) loads.
__global__ void pack_weights(const float* __restrict__ W,
                             const float* __restrict__ b,
                             const int* __restrict__ mask,
                             float* __restrict__ ws) {
    int i = blockIdx.x * blockDim.x + threadIdx.x;
    if (i < 1500) {
        int cin = i / 250;
        int r   = i % 250;
        int dx  = r / 50;
        int r2  = r % 50;
        int dy  = r2 / 10;
        int j   = r2 % 10;
        int cout = CL[cin][j];
        float v = W[((cout * CIN + cin) * 5 + dy) * 5 + dx]
                  * (float)mask[cout * CIN + cin];
        ws[((cin * 5 + dx) * 5 + dy) * 10 + j] = v;
    } else if (i >= BIAS_OFF && i < BIAS_OFF + COUT) {
        ws[i] = b[i - BIAS_OFF];
    }
}

__global__ __launch_bounds__(256, 2)
void conv_main(const float* __restrict__ x,
               const float* __restrict__ ws,
               float* __restrict__ out) {
    __shared__ float tile[CIN * IN_H * IN_W];  // 8160 floats = 32640 B

    const int tid = threadIdx.x;
    const int bw0 = blockIdx.x * TILE_W;
    const int bh0 = blockIdx.y * TILE_H;
    const int b   = blockIdx.z;

    // ---- Stage input tile (all 6 channels, with 2-wide zero halo) ----
    const float* xb = x + (size_t)b * CIN * HW * HW;
    for (int idx = tid; idx < CIN * IN_H * IN_W; idx += 256) {
        int c   = idx % IN_W;
        int t   = idx / IN_W;
        int row = t % IN_H;
        int cin = t / IN_H;
        int gh = bh0 + row - 2;
        int gw = bw0 + c - 2;
        float v = 0.f;
        if ((unsigned)gh < (unsigned)HW && (unsigned)gw < (unsigned)HW)
            v = xb[((size_t)cin * HW + gh) * HW + gw];
        tile[idx] = v;
    }
    __syncthreads();

    // ---- Compute: each thread = 1 column (w) x 4 output rows x 16 couts ----
    const int w  = tid & 63;        // 64 lanes -> consecutive LDS cols, conflict-free
    const int rb = tid >> 6;        // 0..3
    const int h0 = rb * 4;          // first local output row of this thread

    float acc[4][COUT];
#pragma unroll
    for (int r = 0; r < 4; ++r)
#pragma unroll
        for (int o = 0; o < COUT; ++o) acc[r][o] = 0.f;

#pragma unroll
    for (int cin = 0; cin < CIN; ++cin) {
        const float* tp = &tile[((size_t)cin * IN_H + h0) * IN_W + w];
#pragma unroll
        for (int dx = 0; dx < 5; ++dx) {
            // 8 rows of x serve 4 output rows x 5 dy taps
            float xv[8];
#pragma unroll
            for (int rr = 0; rr < 8; ++rr)
                xv[rr] = tp[rr * IN_W + dx];
            const float* wp = ws + (cin * 5 + dx) * 50;  // uniform -> s_load
#pragma unroll
            for (int dy = 0; dy < 5; ++dy) {
#pragma unroll
                for (int j = 0; j < 10; ++j) {
                    const float wv = wp[dy * 10 + j];
                    const int o = CL[cin][j];       // compile-time (cin,j unrolled)
#pragma unroll
                    for (int r = 0; r < 4; ++r)
                        acc[r][o] = fmaf(wv, xv[r + dy], acc[r][o]);
                }
            }
        }
    }

    // ---- Epilogue: add bias, store coalesced dwords ----
    const float* bias = ws + BIAS_OFF;
    float bv[COUT];
#pragma unroll
    for (int o = 0; o < COUT; ++o) bv[o] = bias[o];

    float* ob = out + (size_t)b * COUT * HW * HW
                    + (size_t)(bh0 + h0) * HW + (bw0 + w);
#pragma unroll
    for (int o = 0; o < COUT; ++o) {
#pragma unroll
        for (int r = 0; r < 4; ++r) {
            ob[(size_t)o * HW * HW + (size_t)r * HW] = acc[r][o] + bv[o];
        }
    }
}

extern "C" void kernel_launch(void* const* d_in, const int* in_sizes, int n_in,
                              void* d_out, int out_size, void* d_ws, size_t ws_size,
                              hipStream_t stream) {
    const float* x    = (const float*)d_in[0];
    const float* W    = (const float*)d_in[1];
    const float* b    = (const float*)d_in[2];
    const int*   mask = (const int*)d_in[3];
    float* ws  = (float*)d_ws;
    float* out = (float*)d_out;

    hipLaunchKernelGGL(pack_weights, dim3(7), dim3(256), 0, stream, W, b, mask, ws);

    dim3 grid(HW / TILE_W, HW / TILE_H, 32);   // 8 x 32 x 32 = 8192 blocks
    hipLaunchKernelGGL(conv_main, grid, dim3(256), 0, stream, x, ws, out);
}